// Round 1
// baseline (189.752 us; speedup 1.0000x reference)
//
#include <hip/hip_runtime.h>
#include <cstddef>

#define BB 8
#define CC 512
#define LL 2048
#define TT 64

typedef short short8 __attribute__((ext_vector_type(8)));
typedef float floatx4 __attribute__((ext_vector_type(4)));
typedef unsigned short b16u;
typedef unsigned int u32;

static __device__ __forceinline__ unsigned f2bfu(float f) {
    unsigned u = __float_as_uint(f);
    u += 0x7fffu + ((u >> 16) & 1u);          // round-to-nearest-even
    return u >> 16;
}
static __device__ __forceinline__ float bfu2f(unsigned h) {
    return __uint_as_float(h << 16);
}

#define MFMA16(a, b, c) __builtin_amdgcn_mfma_f32_16x16x32_bf16((a), (b), (c), 0, 0, 0)

// ---------------------------------------------------------------------------
// K0: W1,W2 (64x512 fp32) -> bf16 hi/lo split, row-major.  (unchanged)
// ---------------------------------------------------------------------------
__global__ __launch_bounds__(256) void wcvt_kernel(
    const float* __restrict__ W1, const float* __restrict__ W2,
    b16u* __restrict__ W1h, b16u* __restrict__ W1l,
    b16u* __restrict__ W2h, b16u* __restrict__ W2l)
{
    int flat = blockIdx.x * 256 + threadIdx.x;        // 0..8191 float4 groups
    float4 v1 = *(const float4*)(W1 + (size_t)flat * 4);
    float4 v2 = *(const float4*)(W2 + (size_t)flat * 4);
    const float* e1 = (const float*)&v1;
    const float* e2 = (const float*)&v2;
    unsigned h1[4], l1[4], h2[4], l2[4];
#pragma unroll
    for (int k = 0; k < 4; ++k) {
        h1[k] = f2bfu(e1[k]); l1[k] = f2bfu(e1[k] - bfu2f(h1[k]));
        h2[k] = f2bfu(e2[k]); l2[k] = f2bfu(e2[k] - bfu2f(h2[k]));
    }
    uint2 a, b, c, d;
    a.x = h1[0] | (h1[1] << 16); a.y = h1[2] | (h1[3] << 16);
    b.x = l1[0] | (l1[1] << 16); b.y = l1[2] | (l1[3] << 16);
    c.x = h2[0] | (h2[1] << 16); c.y = h2[2] | (h2[3] << 16);
    d.x = l2[0] | (l2[1] << 16); d.y = l2[2] | (l2[3] << 16);
    *(uint2*)(W1h + (size_t)flat * 4) = a;
    *(uint2*)(W1l + (size_t)flat * 4) = b;
    *(uint2*)(W2h + (size_t)flat * 4) = c;
    *(uint2*)(W2l + (size_t)flat * 4) = d;
}

// ---------------------------------------------------------------------------
// K1: merged cvt+qk (unchanged): Q = W1@X, K = W2@X via split-bf16
// MFMA (hh+hl+lh) -> Qt/Kt (b, l, 64t) bf16.  grid (32 l-tiles, 8 b).
// ---------------------------------------------------------------------------
__global__ __launch_bounds__(256) void qkcvt_kernel(
    const float* __restrict__ x,
    const b16u* __restrict__ W1h, const b16u* __restrict__ W1l,
    const b16u* __restrict__ W2h, const b16u* __restrict__ W2l,
    b16u* __restrict__ Qt, b16u* __restrict__ Kt)
{
    __shared__ b16u Sxh[64 * 72];   // [l][c-chunk]
    __shared__ b16u Sxl[64 * 72];
    __shared__ b16u S1h[64 * 72];   // [t][c-chunk]
    __shared__ b16u S1l[64 * 72];
    __shared__ b16u S2h[64 * 72];
    __shared__ b16u S2l[64 * 72];
    const int b  = blockIdx.y;
    const int l0 = blockIdx.x * 64;
    const int tid = threadIdx.x;
    const int lane = tid & 63;
    const int w = tid >> 6;
    const int n16 = lane & 15;
    const int qd = lane >> 4;
    const float* xb = x + (size_t)b * CC * LL;

    const int cx = tid >> 2;
    const int sx = tid & 3;

    float4 xreg[4];
#pragma unroll
    for (int p = 0; p < 4; ++p)
        xreg[p] = *(const float4*)(xb + (size_t)cx * LL + l0 + (sx * 4 + p) * 4);

    floatx4 aq[4], ak[4];
#pragma unroll
    for (int nt = 0; nt < 4; ++nt) {
        aq[nt] = (floatx4){0.f, 0.f, 0.f, 0.f};
        ak[nt] = (floatx4){0.f, 0.f, 0.f, 0.f};
    }

    for (int c0 = 0; c0 < 512; c0 += 64) {
        __syncthreads();
#pragma unroll
        for (int p = 0; p < 4; ++p) {
            const float* e = (const float*)&xreg[p];
            int lbase = (sx * 4 + p) * 4;
#pragma unroll
            for (int k = 0; k < 4; ++k) {
                unsigned h = f2bfu(e[k]);
                unsigned lo = f2bfu(e[k] - bfu2f(h));
                Sxh[(lbase + k) * 72 + cx] = (b16u)h;
                Sxl[(lbase + k) * 72 + cx] = (b16u)lo;
            }
        }
#pragma unroll
        for (int p = 0; p < 2; ++p) {
            int flat = tid + p * 256;
            int t = flat >> 3, s8 = flat & 7;
            size_t off = (size_t)t * 512 + c0 + s8 * 8;
            *(uint4*)&S1h[t * 72 + s8 * 8] = *(const uint4*)(W1h + off);
            *(uint4*)&S1l[t * 72 + s8 * 8] = *(const uint4*)(W1l + off);
            *(uint4*)&S2h[t * 72 + s8 * 8] = *(const uint4*)(W2h + off);
            *(uint4*)&S2l[t * 72 + s8 * 8] = *(const uint4*)(W2l + off);
        }
        __syncthreads();
        if (c0 < 448) {
#pragma unroll
            for (int p = 0; p < 4; ++p)
                xreg[p] = *(const float4*)(xb + (size_t)(c0 + 64 + cx) * LL +
                                           l0 + (sx * 4 + p) * 4);
        }
#pragma unroll
        for (int kc = 0; kc < 2; ++kc) {
            const int ao = (w * 16 + n16) * 72 + kc * 32 + qd * 8;
            short8 a1h = *(const short8*)&S1h[ao];
            short8 a1l = *(const short8*)&S1l[ao];
            short8 a2h = *(const short8*)&S2h[ao];
            short8 a2l = *(const short8*)&S2l[ao];
#pragma unroll
            for (int nt = 0; nt < 4; ++nt) {
                const int bo = (nt * 16 + n16) * 72 + kc * 32 + qd * 8;
                short8 bh = *(const short8*)&Sxh[bo];
                short8 bl = *(const short8*)&Sxl[bo];
                aq[nt] = MFMA16(a1h, bh, aq[nt]);
                aq[nt] = MFMA16(a1h, bl, aq[nt]);
                aq[nt] = MFMA16(a1l, bh, aq[nt]);
                ak[nt] = MFMA16(a2h, bh, ak[nt]);
                ak[nt] = MFMA16(a2h, bl, ak[nt]);
                ak[nt] = MFMA16(a2l, bh, ak[nt]);
            }
        }
    }
#pragma unroll
    for (int nt = 0; nt < 4; ++nt) {
        int l = l0 + nt * 16 + n16;
        uint2 pq, pk;
        pq.x = f2bfu(aq[nt][0]) | (f2bfu(aq[nt][1]) << 16);
        pq.y = f2bfu(aq[nt][2]) | (f2bfu(aq[nt][3]) << 16);
        pk.x = f2bfu(ak[nt][0]) | (f2bfu(ak[nt][1]) << 16);
        pk.y = f2bfu(ak[nt][2]) | (f2bfu(ak[nt][3]) << 16);
        *(uint2*)(Qt + ((size_t)(b * 2048) + l) * 64 + w * 16 + qd * 4) = pq;
        *(uint2*)(Kt + ((size_t)(b * 2048) + l) * 64 + w * 16 + qd * 4) = pk;
    }
}

// ---------------------------------------------------------------------------
// K2: x -> XT bf16, plain (b, c, l) layout (V is now read directly from L2
// by the fused kernel; no LDS-staging swizzle needed anymore).
// ---------------------------------------------------------------------------
__global__ __launch_bounds__(256) void xcvt_kernel(
    const float* __restrict__ x, b16u* __restrict__ XT)
{
    size_t idx = ((size_t)blockIdx.x * 256 + threadIdx.x) * 4;
    float4 v = *(const float4*)(x + idx);
    uint2 wv;
    wv.x = f2bfu(v.x) | (f2bfu(v.y) << 16);
    wv.y = f2bfu(v.z) | (f2bfu(v.w) << 16);
    *(uint2*)(XT + idx) = wv;
}

// ---------------------------------------------------------------------------
// K3: fused flash-style attention: per block (j-tile=64, one batch), loop
// 32 i-tiles: S^T = K@Q^T (4 MFMA/wave) -> exp(S-20) -> bf16 P staged in
// XOR-swizzled double-buffered LDS -> O += V@P^T (32 MFMA/wave).  Z
// accumulated in-register; epilogue normalizes (g/Z), adds residual x,
// LDS-staged coalesced store.  Eliminates the 67 MB P matrix entirely.
// grid 256 (= 1 block/CU; blockIdx&7 = batch so each XCD L2 caches one
// 2 MB XT slab), block 512 (8 waves: wave w owns c-quadrant w*64..+63,
// and S-quadrant (wi=w&3 -> i-rows, wj2=w>>2 -> j-half)).
// ---------------------------------------------------------------------------
__global__ __launch_bounds__(512, 2) void fused_kernel(
    const float* __restrict__ x, const b16u* __restrict__ XT,
    const b16u* __restrict__ Qt, const b16u* __restrict__ Kt,
    const float* __restrict__ gamma, float* __restrict__ out)
{
    // union layout: loop uses Pb (16 KB) + Zw (1 KB); epilogue reuses the
    // whole region as per-wave staging st (8 x 17408 B); Zf lives past it.
    __shared__ __align__(16) char smem[139264 + 256];
    b16u*  Pb = (b16u*)smem;                    // [2][64][64] shorts, swizzled
    float* Zw = (float*)(smem + 16384);         // [8][32]
    float* Zf = (float*)(smem + 139264);        // [64]

    const int b   = blockIdx.x & 7;
    const int j0  = (blockIdx.x >> 3) * 64;
    const int tid = threadIdx.x;
    const int lane = tid & 63;
    const int w    = tid >> 6;
    const int n16  = lane & 15;
    const int qd   = lane >> 4;
    const int wi   = w & 3;        // i-quadrant for S
    const int wj2  = w >> 2;       // j-half for S

    const b16u* Qb = Qt + ((size_t)(b * LL) + j0 + wj2 * 32 + n16) * 64 + qd * 8;
    const b16u* Kb = Kt + ((size_t)(b * LL) + wi * 16 + n16) * 64 + qd * 8;
    const b16u* Vb = XT + ((size_t)(b * CC) + w * 64 + n16) * 2048 + qd * 8;

    // loop-invariant Q B-fragments (wave's S j-cols)
    short8 qf[2][2];
#pragma unroll
    for (int nt2 = 0; nt2 < 2; ++nt2)
#pragma unroll
        for (int kc = 0; kc < 2; ++kc)
            qf[nt2][kc] = *(const short8*)(Qb + nt2 * (16 * 64) + kc * 32);

    floatx4 acc[4][4];
#pragma unroll
    for (int mt = 0; mt < 4; ++mt)
#pragma unroll
        for (int nt = 0; nt < 4; ++nt) acc[mt][nt] = (floatx4){0.f, 0.f, 0.f, 0.f};
    float zacc[2] = {0.f, 0.f};

    // S^T tile for i-tile: D[m=i-local, n=j]; lane holds 4 consecutive i at
    // fixed j -> 8B ds_write into 16B-chunk-XOR-swizzled row (key j&7).
#define S_STEP(BUFOFF, KF)                                                     \
    {                                                                          \
        _Pragma("unroll")                                                      \
        for (int nt2 = 0; nt2 < 2; ++nt2) {                                    \
            floatx4 sacc = (floatx4){0.f, 0.f, 0.f, 0.f};                      \
            sacc = MFMA16(KF[0], qf[nt2][0], sacc);                            \
            sacc = MFMA16(KF[1], qf[nt2][1], sacc);                            \
            float p0 = __expf(sacc[0] - 20.0f);                                \
            float p1 = __expf(sacc[1] - 20.0f);                                \
            float p2 = __expf(sacc[2] - 20.0f);                                \
            float p3 = __expf(sacc[3] - 20.0f);                                \
            zacc[nt2] += (p0 + p1) + (p2 + p3);                                \
            uint2 pk;                                                          \
            pk.x = f2bfu(p0) | (f2bfu(p1) << 16);                              \
            pk.y = f2bfu(p2) | (f2bfu(p3) << 16);                              \
            int jl = wj2 * 32 + nt2 * 16 + n16;                                \
            int phys = (wi * 2 + (qd >> 1)) ^ (jl & 7);                        \
            *(uint2*)&Pb[(BUFOFF) + jl * 64 + phys * 8 + (qd & 1) * 4] = pk;   \
        }                                                                      \
    }

    // prologue: S(0) -> buf0 (direct K load, one-time stall), prefetch K(1)
    short8 kf[2];
    kf[0] = *(const short8*)(Kb);
    kf[1] = *(const short8*)(Kb + 32);
    S_STEP(0, kf)
    kf[0] = *(const short8*)(Kb + 64 * 64);
    kf[1] = *(const short8*)(Kb + 64 * 64 + 32);
    __syncthreads();

    int buf = 0;
    for (int t = 0; t < 32; ++t) {
        // V fragments for tile t (consumed after the S phase -> L2 latency
        // hides under S MFMAs + exp)
        short8 av[4][2];
#pragma unroll
        for (int mt = 0; mt < 4; ++mt)
#pragma unroll
            for (int kc = 0; kc < 2; ++kc)
                av[mt][kc] = *(const short8*)(Vb + (size_t)mt * (16 * 2048) +
                                              t * 64 + kc * 32);
        if (t < 31) {
            S_STEP((buf ^ 1) * 4096, kf)       // S(t+1) -> other buffer
            if (t < 30) {
                const b16u* kp = Kb + (size_t)(t + 2) * (64 * 64);
                kf[0] = *(const short8*)(kp);
                kf[1] = *(const short8*)(kp + 32);
            }
        }
        // PV(t): P from LDS (swizzled, 2-way = free), V from regs
        __builtin_amdgcn_s_setprio(1);
#pragma unroll
        for (int kc = 0; kc < 2; ++kc) {
            short8 bfr[4];
#pragma unroll
            for (int nt = 0; nt < 4; ++nt) {
                int phys = (kc * 4 + qd) ^ (n16 & 7);
                bfr[nt] = *(const short8*)&Pb[buf * 4096 +
                                              (nt * 16 + n16) * 64 + phys * 8];
            }
#pragma unroll
            for (int mt = 0; mt < 4; ++mt)
#pragma unroll
                for (int nt = 0; nt < 4; ++nt)
                    acc[mt][nt] = MFMA16(av[mt][kc], bfr[nt], acc[mt][nt]);
        }
        __builtin_amdgcn_s_setprio(0);
        __syncthreads();                        // orders buf reads vs next writes
        buf ^= 1;
    }
#undef S_STEP

    // ---- Z: reduce over qd (shfl), then over the 4 i-quadrant waves ----
#pragma unroll
    for (int nt2 = 0; nt2 < 2; ++nt2) {
        float z = zacc[nt2];
        z += __shfl_xor(z, 16);
        z += __shfl_xor(z, 32);
        if (qd == 0) Zw[w * 32 + nt2 * 16 + n16] = z;
    }
    __syncthreads();
    if (tid < 64) {
        int g2 = (tid >> 5) * 4;               // wave group with matching wj2
        Zf[tid] = Zw[(g2 + 0) * 32 + (tid & 31)] + Zw[(g2 + 1) * 32 + (tid & 31)] +
                  Zw[(g2 + 2) * 32 + (tid & 31)] + Zw[(g2 + 3) * 32 + (tid & 31)];
    }
    __syncthreads();

    // ---- epilogue: scale by g/Z, per-wave LDS staging, coalesced store ----
    const float g = gamma[0];
    float* st = (float*)(smem + w * 17408);     // 64 x 68 floats per wave
#pragma unroll
    for (int nt = 0; nt < 4; ++nt) {
        float zi = g / Zf[nt * 16 + n16];
#pragma unroll
        for (int mt = 0; mt < 4; ++mt)
#pragma unroll
            for (int r = 0; r < 4; ++r)
                st[(mt * 16 + qd * 4 + r) * 68 + nt * 16 + n16] = acc[mt][nt][r] * zi;
    }
    __syncthreads();
#pragma unroll
    for (int p = 0; p < 16; ++p) {
        int rl = qd * 16 + p;                   // c-local row in wave's quadrant
        size_t go = ((size_t)(b * CC) + w * 64 + rl) * 2048 + j0 + n16 * 4;
        float4 v = *(const float4*)&st[rl * 68 + n16 * 4];
        float4 xv = *(const float4*)(x + go);
        v.x += xv.x; v.y += xv.y; v.z += xv.z; v.w += xv.w;
        *(float4*)(out + go) = v;
    }
}

// ---------------------------------------------------------------------------
extern "C" void kernel_launch(void* const* d_in, const int* in_sizes, int n_in,
                              void* d_out, int out_size, void* d_ws, size_t ws_size,
                              hipStream_t stream)
{
    (void)in_sizes; (void)n_in; (void)out_size; (void)ws_size;
    const float* x     = (const float*)d_in[0];
    const float* W1    = (const float*)d_in[1];
    const float* W2    = (const float*)d_in[2];
    const float* gamma = (const float*)d_in[3];
    float* out = (float*)d_out;

    b16u* Qt  = (b16u*)d_ws;                        // 2 MB
    b16u* Kt  = Qt  + (size_t)BB * LL * TT;         // 2 MB
    b16u* W1h = Kt  + (size_t)BB * LL * TT;         // 64 KB x4
    b16u* W1l = W1h + (size_t)TT * CC;
    b16u* W2h = W1l + (size_t)TT * CC;
    b16u* W2l = W2h + (size_t)TT * CC;
    b16u* XT  = W2l + (size_t)TT * CC;              // 16.8 MB, (b,c,l) bf16

    wcvt_kernel <<<dim3(32),      256, 0, stream>>>(W1, W2, W1h, W1l, W2h, W2l);
    xcvt_kernel <<<dim3(8192),    256, 0, stream>>>(x, XT);
    qkcvt_kernel<<<dim3(32, BB),  256, 0, stream>>>(x, W1h, W1l, W2h, W2l, Qt, Kt);
    fused_kernel<<<dim3(256),     512, 0, stream>>>(x, XT, Qt, Kt, gamma, out);
}